// Round 5
// baseline (121.679 us; speedup 1.0000x reference)
//
#include <hip/hip_runtime.h>
#include <math.h>

// DiffKS: time-varying 7-tap sparse IIR.
//   y[n] = x[n] + sum_{i=0..6} block_i[n] * y[n - zc[n] - i],  zc in [37,97].
// Max lag 103 -> 103-sample state. Linear => segmented superposition:
//   phase1: per (batch,segment) run 103 unit-state + 1 particular IIRs.
//           ROUND-14: hist transposed to per-run-pair CHUNKS. Lane l owns
//           runs 2l,2l+1 in chunk l ([row*2+sub], stride 532 floats: 16B
//           aligned, 5l mod 8 bank-quad spread). The 7 taps = 14 consecutive
//           floats -> 4 ds_read_b128 (wave-uniform aligned window, even/odd
//           static extraction) instead of 7 ds_read_b64. LDS wave-insts
//           per round ~360 -> ~264 (phase1 is LDS-inst-issue bound: VALU
//           shaving in rounds 2/4 was neutral).
//   phase2: serial state composition, coalesced split-K (round-8 spill-proof
//           macro: tvA/tvB always statically indexed).
//   phase3: exact per-segment re-run with known incoming state (256 blocks).
// DEAD ENDS (do not revisit): round-10 hand-rolled cross-block spin flags
// (124us) and round-12 cooperative grid-sync (264us, ~100us/sync) -- any
// cross-block sync >> the ~2-4us kernel boundary it replaces. Cg coeff
// detour (round-2): +16.8MB HBM round-trip, regressed.

#define B_    16
#define N_    16384
#define S_    16
#define NSEG  1024
#define NITER 28      // ceil(1024/37) for phase3
#define RUNS  104     // 103 unit columns + 1 particular
#define CHUNK 37      // min dependency distance (zc >= 37)
#define CH_STRIDE 532 // floats per chunk: 263 rows x 2 runs = 526, pad to 532
                      // (16B-aligned; 133 float4 -> quad = 5l mod 8, uniform)

#define TG_FLOATS (B_ * S_ * RUNS * RUNS)
#define ST_FLOATS (B_ * S_ * RUNS)

// ---- shared coeff math (proven round-2..8 formulas) ----
__device__ __forceinline__ void diffks_coeffs(float f0v, float lbg, float lbp,
                                              int n, float4& lo, float4& hi) {
  float g  = 0.99f * lbg;
  float p  = lbp;
  float b0 = g * (1.0f - p);
  float a1 = g * p;
  float f0c = f0v - a1 / (b0 + a1 + 1e-7f);
  int   zc  = (int)floorf(f0c) - 2;
  float alpha = f0c - (float)zc;
  float u0 = alpha;
  float u1 = alpha - 1.0f;
  float u2 = alpha - 2.0f;
  float u3 = alpha - 3.0f;
  float u4 = alpha - 4.0f;
  float u5 = alpha - 5.0f;
  float w0 = u1 * u2 * u3 * u4 * u5 * (-1.0f / 120.0f);
  float w1 = u0 * u2 * u3 * u4 * u5 * ( 1.0f /  24.0f);
  float w2 = u0 * u1 * u3 * u4 * u5 * (-1.0f /  12.0f);
  float w3 = u0 * u1 * u2 * u4 * u5 * ( 1.0f /  12.0f);
  float w4 = u0 * u1 * u2 * u3 * u5 * (-1.0f /  24.0f);
  float w5 = u0 * u1 * u2 * u3 * u4 * ( 1.0f / 120.0f);
  lo.x = b0 * w0;                   // block0
  lo.y = fmaf(b0, w1, a1 * w0);     // block1
  lo.z = fmaf(b0, w2, a1 * w1);     // block2
  lo.w = fmaf(b0, w3, a1 * w2);     // block3
  hi.x = fmaf(b0, w4, a1 * w3);     // block4
  hi.y = fmaf(b0, w5, a1 * w4);     // block5
  hi.z = a1 * w5;                   // block6
  hi.w = __int_as_float((n - 6 - zc) & 255);   // ring base row (pos mod 256)
}

// =================== Phase 1: T matrices (chunked hist) ===================
// grid 256 (= b*16+s), block 1024 = 16 waves. Wave w processes samples
// 32t+2w, 32t+2w+1 in round t; lane l owns runs 2l,2l+1 (chunk l).
// Chunk layout: float [row*2 + sub]; rows 0..255 ring (pos mod 256), rows
// 256..262 mirror rows 0..6 so tap windows never wrap. Taps for sample p:
// rows base..base+6 = floats [2*base .. 2*base+13] -> 4 aligned b128 reads
// at w0=(2*base)&~3, extracted by wave-uniform (base&1) branch.
__global__ __launch_bounds__(1024) void diffks_phase1(
    const float* __restrict__ f0, const float* __restrict__ lb,
    const float* __restrict__ x, float* __restrict__ Tg) {
  const int bs = blockIdx.x;
  const int b  = bs >> 4, s = bs & 15;
  const int n0 = s << 10;
  const int tid = threadIdx.x;

  __shared__ __align__(16) float hist[52 * CH_STRIDE]; // 108.1 KB
  __shared__ float4 sLo[NSEG], sHi[NSEG];              // 32 KB
  __shared__ float  sX[NSEG];                          // 4 KB

  {
    const size_t gi = (size_t)b * N_ + n0 + tid;
    const float2 lv = ((const float2*)lb)[gi];
    float4 lo, hi;
    diffks_coeffs(f0[gi], lv.x, lv.y, tid, lo, hi);
    sLo[tid] = lo; sHi[tid] = hi; sX[tid] = x[gi];
  }
  // Zero-init rows 152..263 of every chunk (float4 [76..132) per chunk):
  // rows 0..152 are written (sample p -> row p) before any read; only the
  // initial-state rows 153..255 need zeros (+ slack covering window overreads).
  {
    for (int i = tid; i < 52 * 56; i += 1024) {
      const int c = i / 56, k = i - c * 56;
      ((float4*)hist)[c * (CH_STRIDE / 4) + 76 + k] =
          float4{0.0f, 0.0f, 0.0f, 0.0f};
    }
  }
  __syncthreads();
  if (tid < 103) {
    // e_r at position -1-r -> row 255-r, chunk r>>1, sub r&1
    hist[(tid >> 1) * CH_STRIDE + (255 - tid) * 2 + (tid & 1)] = 1.0f;
  }
  __syncthreads();

  {
    const int w    = tid >> 6;      // wave 0..15
    const int lane = tid & 63;
    const bool act = (lane < 52);
    const bool px  = (lane == 51);  // .y of lane 51 is run 103 (particular)
    float* __restrict__ hcol = hist + lane * CH_STRIDE;  // chunk base

    for (int t = 0; t < 32; ++t) {
#pragma unroll
      for (int u = 0; u < 2; ++u) {
        const int p = 32 * t + 2 * w + u;     // 32 consecutive samples/round
        const float4 lo = sLo[p];             // wave-uniform -> broadcast
        const float4 hi = sHi[p];
        const float  xv = sX[p];
        if (act) {
          const int base = __float_as_int(hi.w);   // row of oldest tap, 0..255
          const int w0 = (2 * base) & ~3;          // aligned window (floats)
          const float4* __restrict__ hw = (const float4*)(hcol + w0);
          const float4 v0 = hw[0];                 // imm offsets 0/16/32/48
          const float4 v1 = hw[1];
          const float4 v2 = hw[2];
          const float4 v3 = hw[3];
          float ax = 0.0f;
          float ay = px ? xv : 0.0f;
          if ((base & 1) == 0) {                   // taps = f[0..13]
            ax = fmaf(hi.z, v0.x, ax); ay = fmaf(hi.z, v0.y, ay);
            ax = fmaf(hi.y, v0.z, ax); ay = fmaf(hi.y, v0.w, ay);
            ax = fmaf(hi.x, v1.x, ax); ay = fmaf(hi.x, v1.y, ay);
            ax = fmaf(lo.w, v1.z, ax); ay = fmaf(lo.w, v1.w, ay);
            ax = fmaf(lo.z, v2.x, ax); ay = fmaf(lo.z, v2.y, ay);
            ax = fmaf(lo.y, v2.z, ax); ay = fmaf(lo.y, v2.w, ay);
            ax = fmaf(lo.x, v3.x, ax); ay = fmaf(lo.x, v3.y, ay);
          } else {                                 // taps = f[2..15]
            ax = fmaf(hi.z, v0.z, ax); ay = fmaf(hi.z, v0.w, ay);
            ax = fmaf(hi.y, v1.x, ax); ay = fmaf(hi.y, v1.y, ay);
            ax = fmaf(hi.x, v1.z, ax); ay = fmaf(hi.x, v1.w, ay);
            ax = fmaf(lo.w, v2.x, ax); ay = fmaf(lo.w, v2.y, ay);
            ax = fmaf(lo.z, v2.z, ax); ay = fmaf(lo.z, v2.w, ay);
            ax = fmaf(lo.y, v3.x, ax); ay = fmaf(lo.y, v3.y, ay);
            ax = fmaf(lo.x, v3.z, ax); ay = fmaf(lo.x, v3.w, ay);
          }
          const int wsl = p & 255;
          float2 acc; acc.x = ax; acc.y = ay;
          *(float2*)(hcol + 2 * wsl) = acc;
          if (wsl < 7)                             // keep mirror rows coherent
            *(float2*)(hcol + 2 * wsl + 512) = acc;
        }
      }
      __syncthreads();   // publish this round's 32 samples to all waves
    }
  }

  // emit RUNS-MAJOR: T[r][j] = run r at position 1023-j (row 255-j)
  float* __restrict__ T = Tg + (size_t)bs * RUNS * RUNS;
  for (int idx = tid; idx < RUNS * RUNS; idx += 1024) {
    const int r = idx / RUNS;
    const int j = idx - r * RUNS;
    T[idx] = (j < 103)
        ? hist[(r >> 1) * CH_STRIDE + (255 - j) * 2 + (r & 1)]
        : 0.0f;
  }
}

// =================== Phase 2: serial state composition ===================
// grid 16 (batch), block 832 = 104 j-threads x 8 k-slices.
// state_{s+1}[j] = sum_{r=0..103} T[r][j] * cur[r], with cur[103] == 1
// (run 103 is the particular tail). Lanes = consecutive j -> coalesced loads.
// Double-buffered prefetch with GUARANTEED static register indexing.
#define P2_STEP(s_, tv_)                                                      \
  {                                                                           \
    if (q == 0) states[((size_t)b * S_ + (s_)) * RUNS + j] = cur[j];          \
    float acc = 0.0f;                                                         \
    _Pragma("unroll")                                                         \
    for (int k = 0; k < 13; ++k) acc = fmaf(tv_[k], cur[r0 + k], acc);        \
    if ((s_) + 2 < S_) {                                                      \
      const float* __restrict__ Tn = Tb + (size_t)((s_) + 2) * RUNS * RUNS;   \
      _Pragma("unroll")                                                       \
      for (int k = 0; k < 13; ++k) tv_[k] = Tn[(size_t)(r0 + k) * RUNS + j];  \
    }                                                                         \
    part[q][j] = acc;                                                         \
    __syncthreads();                                                          \
    if (q == 0) {                                                             \
      float v = 0.0f;                                                         \
      _Pragma("unroll")                                                       \
      for (int qq = 0; qq < 8; ++qq) v += part[qq][j];                        \
      cur[j] = (j < 103) ? v : 1.0f;                                          \
    }                                                                         \
    __syncthreads();                                                          \
  }

__global__ __launch_bounds__(832) void diffks_phase2(
    const float* __restrict__ Tg, float* __restrict__ states) {
  const int b   = blockIdx.x;
  const int tid = threadIdx.x;
  const int j   = tid % RUNS;      // 0..103
  const int q   = tid / RUNS;      // 0..7
  const int r0  = 13 * q;
  __shared__ float cur[RUNS];
  __shared__ float part[8][105];   // 105 stride: conflict-free reduce
  if (tid < 103) cur[tid] = 0.0f;
  if (tid == 103) cur[103] = 1.0f; // particular weight, never overwritten
  __syncthreads();

  const float* __restrict__ Tb = Tg + (size_t)b * S_ * RUNS * RUNS;
  float tvA[13], tvB[13];
#pragma unroll
  for (int k = 0; k < 13; ++k)
    tvA[k] = Tb[(size_t)(r0 + k) * RUNS + j];                       // seg 0
#pragma unroll
  for (int k = 0; k < 13; ++k)
    tvB[k] = Tb[(size_t)RUNS * RUNS + (size_t)(r0 + k) * RUNS + j]; // seg 1

#pragma unroll
  for (int sp = 0; sp < 8; ++sp) {
    P2_STEP(2 * sp,     tvA)
    P2_STEP(2 * sp + 1, tvB)
  }
}

// =================== Phase 3: exact per-segment re-run ===================
// grid 256, block 256 (4 waves): all stage coeffs (recomputed from f0/lb/x:
// 16B/sample), wave 0 runs the 28-iter scan, all flush.
__global__ __launch_bounds__(256) void diffks_phase3(
    const float* __restrict__ f0, const float* __restrict__ lb,
    const float* __restrict__ x, const float* __restrict__ states,
    float* __restrict__ y) {
  const int bs = blockIdx.x;
  const int b  = bs >> 4, s = bs & 15;
  const int n0 = s << 10;
  const int tid = threadIdx.x;

  __shared__ __align__(16) float ring[512];   // mirrored mod-256 ring
  __shared__ float4 sC[2 * NSEG];             // interleaved lo/hi
  __shared__ float  sX[NSEG];
  __shared__ float  sY[NSEG];

#pragma unroll
  for (int k = 0; k < 2; ++k) ring[tid + 256 * k] = 0.0f;
  {
    const size_t gb = (size_t)b * N_ + n0;
    const float*  __restrict__ f0b = f0 + gb;
    const float2* __restrict__ lbb = (const float2*)(lb + 2 * gb);
    const float*  __restrict__ xb  = x + gb;
    // batch all 4 rounds of loads, then compute
    float  vf[4]; float2 vl[4]; float vx[4];
#pragma unroll
    for (int k = 0; k < 4; ++k) {
      const int i = tid + 256 * k;
      vf[k] = f0b[i]; vl[k] = lbb[i]; vx[k] = xb[i];
    }
#pragma unroll
    for (int k = 0; k < 4; ++k) {
      const int i = tid + 256 * k;
      float4 lo, hi;
      diffks_coeffs(vf[k], vl[k].x, vl[k].y, n0 + i, lo, hi);
      sC[2 * i] = lo; sC[2 * i + 1] = hi; sX[i] = vx[k];
    }
  }
  __syncthreads();
  // incoming state k at position n0-1-k -> row 255-k (+ mirror). Hot-loop
  // writes only reach row 255-k at p=255-k > 102-k = last read of state k.
  const float* __restrict__ st = states + (size_t)bs * RUNS;
  if (tid < 103) {
    const float v = st[tid];
    ring[255 - tid] = v;
    ring[511 - tid] = v;
  }
  __syncthreads();

  if (tid < 64) {
    const int lane = tid;
    const bool act = (lane < CHUNK);
    for (int t = 0; t < NITER; ++t) {
      const int p = t * CHUNK + lane;
      if (act && p < NSEG) {
        const float4 lo = sC[2 * p];
        const float4 hi = sC[2 * p + 1];
        const float  xv = sX[p];
        const int base = __float_as_int(hi.w);   // (p-6-zc)&255
        const float r0 = ring[base + 0];
        const float r1 = ring[base + 1];
        const float r2 = ring[base + 2];
        const float r3 = ring[base + 3];
        const float r4 = ring[base + 4];
        const float r5 = ring[base + 5];
        const float r6 = ring[base + 6];
        const float s0 = fmaf(lo.x, r6, xv);
        const float s1 = fmaf(lo.y, r5, lo.z * r4);
        const float s2 = fmaf(lo.w, r3, hi.x * r2);
        const float s3 = fmaf(hi.y, r1, hi.z * r0);
        const float yv = (s0 + s1) + (s2 + s3);
        const int wsl = p & 255;
        ring[wsl]       = yv;
        ring[wsl + 256] = yv;
        sY[p] = yv;
      }
      __builtin_amdgcn_wave_barrier();
      asm volatile("" ::: "memory");
    }
  }
  __syncthreads();

  float4* __restrict__ yb = (float4*)(y + (size_t)b * N_ + n0);
  yb[tid] = ((const float4*)sY)[tid];
}

// =================== Fallback (proven round-2 path) ===================
__global__ __launch_bounds__(256) void diffks_coeff_fb(
    const float* __restrict__ f0, const float* __restrict__ lb,
    float* __restrict__ cw, int total, int Nmask) {
  int idx = blockIdx.x * blockDim.x + threadIdx.x;
  if (idx >= total) return;
  float4 lo, hi;
  diffks_coeffs(f0[idx], lb[2 * idx], lb[2 * idx + 1], idx & Nmask, lo, hi);
  float4* out4 = (float4*)cw;
  out4[2 * idx]     = lo;
  out4[2 * idx + 1] = hi;
}

__global__ __launch_bounds__(64) void diffks_scan_fb(
    const float* __restrict__ x, const float* __restrict__ cw,
    float* __restrict__ y, int N) {
  const int b    = blockIdx.x;
  const int lane = threadIdx.x;
  __shared__ float ring[512];
#pragma unroll
  for (int i = 0; i < 8; ++i) ring[lane + 64 * i] = 0.0f;
  __builtin_amdgcn_wave_barrier();
  asm volatile("" ::: "memory");
  const float4* __restrict__ c4 = (const float4*)(cw + (size_t)b * N * 8);
  const float*  __restrict__ xb = x + (size_t)b * N;
  float*        __restrict__ yb = y + (size_t)b * N;
  const bool act = (lane < CHUNK);
  const int nIter = (N + CHUNK - 1) / CHUNK;
  for (int t = 0; t < nIter; ++t) {
    const int n = t * CHUNK + lane;
    if (act && n < N) {
      const float4 lo = c4[2 * n];
      const float4 hi = c4[2 * n + 1];
      const float  xv = xb[n];
      const int base = __float_as_int(hi.w);
      const float r0 = ring[base + 0];
      const float r1 = ring[base + 1];
      const float r2 = ring[base + 2];
      const float r3 = ring[base + 3];
      const float r4 = ring[base + 4];
      const float r5 = ring[base + 5];
      const float r6 = ring[base + 6];
      const float s0 = fmaf(lo.x, r6, xv);
      const float s1 = fmaf(lo.y, r5, lo.z * r4);
      const float s2 = fmaf(lo.w, r3, hi.x * r2);
      const float s3 = fmaf(hi.y, r1, hi.z * r0);
      const float yv = (s0 + s1) + (s2 + s3);
      ring[n & 255]         = yv;
      ring[(n & 255) + 256] = yv;
      yb[n] = yv;
    }
    __builtin_amdgcn_wave_barrier();
    asm volatile("" ::: "memory");
  }
}

extern "C" void kernel_launch(void* const* d_in, const int* in_sizes, int n_in,
                              void* d_out, int out_size, void* d_ws, size_t ws_size,
                              hipStream_t stream) {
  const float* f0 = (const float*)d_in[0];
  const float* x  = (const float*)d_in[1];
  const float* lb = (const float*)d_in[2];
  float* out = (float*)d_out;

  const int total = in_sizes[0];
  const size_t need = (size_t)(TG_FLOATS + ST_FLOATS) * 4;

  if (total == B_ * N_ && ws_size >= need) {
    float* Tg = (float*)d_ws;
    float* st = Tg + TG_FLOATS;
    diffks_phase1<<<B_ * S_, 1024, 0, stream>>>(f0, lb, x, Tg);
    diffks_phase2<<<B_, 832, 0, stream>>>(Tg, st);
    diffks_phase3<<<B_ * S_, 256, 0, stream>>>(f0, lb, x, st, out);
  } else {
    const int N = total / B_;
    float* cw = (float*)d_ws;
    diffks_coeff_fb<<<(total + 255) / 256, 256, 0, stream>>>(f0, lb, cw, total, N - 1);
    diffks_scan_fb<<<B_, 64, 0, stream>>>(x, cw, out, N);
  }
}

// Round 6
// 108.524 us; speedup vs baseline: 1.1212x; 1.1212x over previous
//
#include <hip/hip_runtime.h>
#include <math.h>

// DiffKS: time-varying 7-tap sparse IIR.
//   y[n] = x[n] + sum_{i=0..6} block_i[n] * y[n - zc[n] - i],  zc in [37,97].
// Max lag 103 -> 103-sample state. Linear => segmented superposition:
//   phase1: per (batch,segment) run 103 unit-state + 1 particular IIRs.
//           ROUND-16: lane = (sample-half, run-quad). Lanes 0..25 own sample
//           A runs 4l..4l+3, lanes 26..51 sample B. Taps = 7 ds_read_b128
//           per wave-round, each half-wave reading 26 CONSECUTIVE float4s of
//           one row-major row (bank-perfect; round-5's chunked layout had
//           8-way WRITE conflicts, 6.1M counted). Coeffs live in registers
//           (lane t caches round-t sample A, lane t+32 sample B) and are
//           broadcast per round via v_readlane (SALU pipe) -- the old
//           sLo/sHi/sX LDS broadcasts were ~28% of round time. DS insts per
//           wave-round: 22 -> 8.
//   phase2: serial state composition, coalesced split-K (round-8 spill-proof
//           macro: tvA/tvB always statically indexed).
//   phase3: exact per-segment re-run with known incoming state (256 blocks).
// DEAD ENDS (do not revisit): cross-block sync in-kernel (spin flags 124us,
// coop grid-sync 264us); Cg coeff detour (+16.8MB HBM, regressed); chunked
// hist layout (write-bank conflicts); byte-equal b128 repacking without
// traffic reduction (sweep-bound, not inst-bound).

#define B_    16
#define N_    16384
#define S_    16
#define NSEG  1024
#define NITER 28      // ceil(1024/37) for phase3
#define RUNS  104     // 103 unit columns + 1 particular
#define CHUNK 37      // min dependency distance (zc >= 37)
#define HROWS 263     // 256 ring rows + 7 mirror rows (rows 256..262 = 0..6)

#define TG_FLOATS (B_ * S_ * RUNS * RUNS)
#define ST_FLOATS (B_ * S_ * RUNS)

#define RL(v, l) __int_as_float(__builtin_amdgcn_readlane(__float_as_int(v), (l)))

// ---- shared coeff math (proven round-2..8 formulas) ----
__device__ __forceinline__ void diffks_coeffs(float f0v, float lbg, float lbp,
                                              int n, float4& lo, float4& hi) {
  float g  = 0.99f * lbg;
  float p  = lbp;
  float b0 = g * (1.0f - p);
  float a1 = g * p;
  float f0c = f0v - a1 / (b0 + a1 + 1e-7f);
  int   zc  = (int)floorf(f0c) - 2;
  float alpha = f0c - (float)zc;
  float u0 = alpha;
  float u1 = alpha - 1.0f;
  float u2 = alpha - 2.0f;
  float u3 = alpha - 3.0f;
  float u4 = alpha - 4.0f;
  float u5 = alpha - 5.0f;
  float w0 = u1 * u2 * u3 * u4 * u5 * (-1.0f / 120.0f);
  float w1 = u0 * u2 * u3 * u4 * u5 * ( 1.0f /  24.0f);
  float w2 = u0 * u1 * u3 * u4 * u5 * (-1.0f /  12.0f);
  float w3 = u0 * u1 * u2 * u4 * u5 * ( 1.0f /  12.0f);
  float w4 = u0 * u1 * u2 * u3 * u5 * (-1.0f /  24.0f);
  float w5 = u0 * u1 * u2 * u3 * u4 * ( 1.0f / 120.0f);
  lo.x = b0 * w0;                   // block0
  lo.y = fmaf(b0, w1, a1 * w0);     // block1
  lo.z = fmaf(b0, w2, a1 * w1);     // block2
  lo.w = fmaf(b0, w3, a1 * w2);     // block3
  hi.x = fmaf(b0, w4, a1 * w3);     // block4
  hi.y = fmaf(b0, w5, a1 * w4);     // block5
  hi.z = a1 * w5;                   // block6
  hi.w = __int_as_float((n - 6 - zc) & 255);   // ring base row (pos mod 256)
}

// =================== Phase 1: T matrices (row-major, reg coeffs) =========
// grid 256 (= b*16+s), block 1024 = 16 waves. Round t: wave w handles
// samples A=32t+2w, B=A+1. Lane l<26: sample A, runs 4l..4l+3; lane
// 26..51: sample B, runs 4(l-26).. ; lanes 52..63 idle in the hot loop
// (they still cache coeffs for readlane).
// hist[row][run] row-major; rows 0..255 = position mod 256; rows 256..262
// mirror rows 0..6 so tap windows [base..base+6] never wrap.
__global__ __launch_bounds__(1024) void diffks_phase1(
    const float* __restrict__ f0, const float* __restrict__ lb,
    const float* __restrict__ x, float* __restrict__ Tg) {
  const int bs = blockIdx.x;
  const int b  = bs >> 4, s = bs & 15;
  const int n0 = s << 10;
  const int tid = threadIdx.x;
  const int w    = tid >> 6;      // wave 0..15
  const int lane = tid & 63;

  __shared__ __align__(16) float hist[HROWS * RUNS]; // 106.8 KB, ONLY array

  // ---- per-lane coeff cache: lane t -> round-t sample A, lane t+32 -> B
  float4 cLo, cHi; float cX;
  {
    const int my_p = 32 * (lane & 31) + 2 * w + (lane >> 5);
    const size_t gi = (size_t)b * N_ + n0 + my_p;
    const float2 lv = ((const float2*)lb)[gi];
    diffks_coeffs(f0[gi], lv.x, lv.y, my_p, cLo, cHi);
    cX = x[gi];
  }

  // Zero rows 152..262 (initial-state rows 153..255 + mirrors + slack).
  // Rows 0..152 are written (sample p -> row p) before any read (earliest
  // read of position p' is sample p'+37, always a later round).
  {
    float4* __restrict__ hz = (float4*)(hist + 152 * RUNS);
    const int nz = ((HROWS - 152) * RUNS) / 4;   // 111*104/4 = 2886
    for (int i = tid; i < nz; i += 1024)
      hz[i] = float4{0.0f, 0.0f, 0.0f, 0.0f};
  }
  __syncthreads();
  if (tid < 103) hist[(255 - tid) * RUNS + tid] = 1.0f;  // e_r at pos -1-r
  __syncthreads();

  {
    const bool half = (lane >= 26);           // 0: sample A, 1: sample B
    const int  l4   = half ? lane - 26 : lane;  // run quad 0..25
    const bool act  = (lane < 52);
    const bool px   = (l4 == 25);             // .w of quad 25 is run 103
    float* __restrict__ hq = hist + 4 * l4;   // quad column base

    for (int t = 0; t < 32; ++t) {
      // broadcast round-t coeffs from cache lanes t (A) and t+32 (B): SALU
      const int lA = t, lB = t + 32;
      const float c0A = RL(cHi.z, lA), c0B = RL(cHi.z, lB);  // block6
      const float c1A = RL(cHi.y, lA), c1B = RL(cHi.y, lB);  // block5
      const float c2A = RL(cHi.x, lA), c2B = RL(cHi.x, lB);  // block4
      const float c3A = RL(cLo.w, lA), c3B = RL(cLo.w, lB);  // block3
      const float c4A = RL(cLo.z, lA), c4B = RL(cLo.z, lB);  // block2
      const float c5A = RL(cLo.y, lA), c5B = RL(cLo.y, lB);  // block1
      const float c6A = RL(cLo.x, lA), c6B = RL(cLo.x, lB);  // block0
      const float bwA = RL(cHi.w, lA), bwB = RL(cHi.w, lB);  // base row bits
      const float xA  = RL(cX,   lA), xB  = RL(cX,   lB);

      if (act) {
        const float c[7] = {half ? c0B : c0A, half ? c1B : c1A,
                            half ? c2B : c2A, half ? c3B : c3A,
                            half ? c4B : c4A, half ? c5B : c5A,
                            half ? c6B : c6A};
        const int   base = __float_as_int(half ? bwB : bwA);  // 0..255
        const float xv   = half ? xB : xA;
        const float4* __restrict__ hr = (const float4*)(hq + base * RUNS);
        float4 a;
        a.x = 0.0f; a.y = 0.0f; a.z = 0.0f;
        a.w = px ? xv : 0.0f;
#pragma unroll
        for (int m = 0; m < 7; ++m) {
          const float4 v = hr[m * 26];        // +m rows = imm offset m*416B
          a.x = fmaf(c[m], v.x, a.x);
          a.y = fmaf(c[m], v.y, a.y);
          a.z = fmaf(c[m], v.z, a.z);
          a.w = fmaf(c[m], v.w, a.w);
        }
        const int p   = 32 * t + 2 * w + (half ? 1 : 0);
        const int wsl = p & 255;
        *(float4*)(hq + wsl * RUNS) = a;
        // mirror rows 0..6 -> 256..262 (wave-uniform round/wave predicate)
        if (((t & 7) == 0) && (w < 4) && (wsl < 7))
          *(float4*)(hq + (wsl + 256) * RUNS) = a;
      }
      __syncthreads();   // publish this round's 32 samples to all waves
    }
  }

  // emit RUNS-MAJOR: T[r][j] = run r at position 1023-j (row 255-j)
  float* __restrict__ T = Tg + (size_t)bs * RUNS * RUNS;
  for (int idx = tid; idx < RUNS * RUNS; idx += 1024) {
    const int r = idx / RUNS;
    const int j = idx - r * RUNS;
    T[idx] = (j < 103) ? hist[(255 - j) * RUNS + r] : 0.0f;
  }
}

// =================== Phase 2: serial state composition ===================
// grid 16 (batch), block 832 = 104 j-threads x 8 k-slices.
// state_{s+1}[j] = sum_{r=0..103} T[r][j] * cur[r], with cur[103] == 1
// (run 103 is the particular tail). Lanes = consecutive j -> coalesced loads.
// Double-buffered prefetch with GUARANTEED static register indexing.
#define P2_STEP(s_, tv_)                                                      \
  {                                                                           \
    if (q == 0) states[((size_t)b * S_ + (s_)) * RUNS + j] = cur[j];          \
    float acc = 0.0f;                                                         \
    _Pragma("unroll")                                                         \
    for (int k = 0; k < 13; ++k) acc = fmaf(tv_[k], cur[r0 + k], acc);        \
    if ((s_) + 2 < S_) {                                                      \
      const float* __restrict__ Tn = Tb + (size_t)((s_) + 2) * RUNS * RUNS;   \
      _Pragma("unroll")                                                       \
      for (int k = 0; k < 13; ++k) tv_[k] = Tn[(size_t)(r0 + k) * RUNS + j];  \
    }                                                                         \
    part[q][j] = acc;                                                         \
    __syncthreads();                                                          \
    if (q == 0) {                                                             \
      float v = 0.0f;                                                         \
      _Pragma("unroll")                                                       \
      for (int qq = 0; qq < 8; ++qq) v += part[qq][j];                        \
      cur[j] = (j < 103) ? v : 1.0f;                                          \
    }                                                                         \
    __syncthreads();                                                          \
  }

__global__ __launch_bounds__(832) void diffks_phase2(
    const float* __restrict__ Tg, float* __restrict__ states) {
  const int b   = blockIdx.x;
  const int tid = threadIdx.x;
  const int j   = tid % RUNS;      // 0..103
  const int q   = tid / RUNS;      // 0..7
  const int r0  = 13 * q;
  __shared__ float cur[RUNS];
  __shared__ float part[8][105];   // 105 stride: conflict-free reduce
  if (tid < 103) cur[tid] = 0.0f;
  if (tid == 103) cur[103] = 1.0f; // particular weight, never overwritten
  __syncthreads();

  const float* __restrict__ Tb = Tg + (size_t)b * S_ * RUNS * RUNS;
  float tvA[13], tvB[13];
#pragma unroll
  for (int k = 0; k < 13; ++k)
    tvA[k] = Tb[(size_t)(r0 + k) * RUNS + j];                       // seg 0
#pragma unroll
  for (int k = 0; k < 13; ++k)
    tvB[k] = Tb[(size_t)RUNS * RUNS + (size_t)(r0 + k) * RUNS + j]; // seg 1

#pragma unroll
  for (int sp = 0; sp < 8; ++sp) {
    P2_STEP(2 * sp,     tvA)
    P2_STEP(2 * sp + 1, tvB)
  }
}

// =================== Phase 3: exact per-segment re-run ===================
// grid 256, block 256 (4 waves): all stage coeffs (recomputed from f0/lb/x:
// 16B/sample), wave 0 runs the 28-iter scan, all flush.
__global__ __launch_bounds__(256) void diffks_phase3(
    const float* __restrict__ f0, const float* __restrict__ lb,
    const float* __restrict__ x, const float* __restrict__ states,
    float* __restrict__ y) {
  const int bs = blockIdx.x;
  const int b  = bs >> 4, s = bs & 15;
  const int n0 = s << 10;
  const int tid = threadIdx.x;

  __shared__ __align__(16) float ring[512];   // mirrored mod-256 ring
  __shared__ float4 sC[2 * NSEG];             // interleaved lo/hi
  __shared__ float  sX[NSEG];
  __shared__ float  sY[NSEG];

#pragma unroll
  for (int k = 0; k < 2; ++k) ring[tid + 256 * k] = 0.0f;
  {
    const size_t gb = (size_t)b * N_ + n0;
    const float*  __restrict__ f0b = f0 + gb;
    const float2* __restrict__ lbb = (const float2*)(lb + 2 * gb);
    const float*  __restrict__ xb  = x + gb;
    // batch all 4 rounds of loads, then compute
    float  vf[4]; float2 vl[4]; float vx[4];
#pragma unroll
    for (int k = 0; k < 4; ++k) {
      const int i = tid + 256 * k;
      vf[k] = f0b[i]; vl[k] = lbb[i]; vx[k] = xb[i];
    }
#pragma unroll
    for (int k = 0; k < 4; ++k) {
      const int i = tid + 256 * k;
      float4 lo, hi;
      diffks_coeffs(vf[k], vl[k].x, vl[k].y, n0 + i, lo, hi);
      sC[2 * i] = lo; sC[2 * i + 1] = hi; sX[i] = vx[k];
    }
  }
  __syncthreads();
  // incoming state k at position n0-1-k -> row 255-k (+ mirror). Hot-loop
  // writes only reach row 255-k at p=255-k > 102-k = last read of state k.
  const float* __restrict__ st = states + (size_t)bs * RUNS;
  if (tid < 103) {
    const float v = st[tid];
    ring[255 - tid] = v;
    ring[511 - tid] = v;
  }
  __syncthreads();

  if (tid < 64) {
    const int lane = tid;
    const bool act = (lane < CHUNK);
    for (int t = 0; t < NITER; ++t) {
      const int p = t * CHUNK + lane;
      if (act && p < NSEG) {
        const float4 lo = sC[2 * p];
        const float4 hi = sC[2 * p + 1];
        const float  xv = sX[p];
        const int base = __float_as_int(hi.w);   // (p-6-zc)&255
        const float r0 = ring[base + 0];
        const float r1 = ring[base + 1];
        const float r2 = ring[base + 2];
        const float r3 = ring[base + 3];
        const float r4 = ring[base + 4];
        const float r5 = ring[base + 5];
        const float r6 = ring[base + 6];
        const float s0 = fmaf(lo.x, r6, xv);
        const float s1 = fmaf(lo.y, r5, lo.z * r4);
        const float s2 = fmaf(lo.w, r3, hi.x * r2);
        const float s3 = fmaf(hi.y, r1, hi.z * r0);
        const float yv = (s0 + s1) + (s2 + s3);
        const int wsl = p & 255;
        ring[wsl]       = yv;
        ring[wsl + 256] = yv;
        sY[p] = yv;
      }
      __builtin_amdgcn_wave_barrier();
      asm volatile("" ::: "memory");
    }
  }
  __syncthreads();

  float4* __restrict__ yb = (float4*)(y + (size_t)b * N_ + n0);
  yb[tid] = ((const float4*)sY)[tid];
}

// =================== Fallback (proven round-2 path) ===================
__global__ __launch_bounds__(256) void diffks_coeff_fb(
    const float* __restrict__ f0, const float* __restrict__ lb,
    float* __restrict__ cw, int total, int Nmask) {
  int idx = blockIdx.x * blockDim.x + threadIdx.x;
  if (idx >= total) return;
  float4 lo, hi;
  diffks_coeffs(f0[idx], lb[2 * idx], lb[2 * idx + 1], idx & Nmask, lo, hi);
  float4* out4 = (float4*)cw;
  out4[2 * idx]     = lo;
  out4[2 * idx + 1] = hi;
}

__global__ __launch_bounds__(64) void diffks_scan_fb(
    const float* __restrict__ x, const float* __restrict__ cw,
    float* __restrict__ y, int N) {
  const int b    = blockIdx.x;
  const int lane = threadIdx.x;
  __shared__ float ring[512];
#pragma unroll
  for (int i = 0; i < 8; ++i) ring[lane + 64 * i] = 0.0f;
  __builtin_amdgcn_wave_barrier();
  asm volatile("" ::: "memory");
  const float4* __restrict__ c4 = (const float4*)(cw + (size_t)b * N * 8);
  const float*  __restrict__ xb = x + (size_t)b * N;
  float*        __restrict__ yb = y + (size_t)b * N;
  const bool act = (lane < CHUNK);
  const int nIter = (N + CHUNK - 1) / CHUNK;
  for (int t = 0; t < nIter; ++t) {
    const int n = t * CHUNK + lane;
    if (act && n < N) {
      const float4 lo = c4[2 * n];
      const float4 hi = c4[2 * n + 1];
      const float  xv = xb[n];
      const int base = __float_as_int(hi.w);
      const float r0 = ring[base + 0];
      const float r1 = ring[base + 1];
      const float r2 = ring[base + 2];
      const float r3 = ring[base + 3];
      const float r4 = ring[base + 4];
      const float r5 = ring[base + 5];
      const float r6 = ring[base + 6];
      const float s0 = fmaf(lo.x, r6, xv);
      const float s1 = fmaf(lo.y, r5, lo.z * r4);
      const float s2 = fmaf(lo.w, r3, hi.x * r2);
      const float s3 = fmaf(hi.y, r1, hi.z * r0);
      const float yv = (s0 + s1) + (s2 + s3);
      ring[n & 255]         = yv;
      ring[(n & 255) + 256] = yv;
      yb[n] = yv;
    }
    __builtin_amdgcn_wave_barrier();
    asm volatile("" ::: "memory");
  }
}

extern "C" void kernel_launch(void* const* d_in, const int* in_sizes, int n_in,
                              void* d_out, int out_size, void* d_ws, size_t ws_size,
                              hipStream_t stream) {
  const float* f0 = (const float*)d_in[0];
  const float* x  = (const float*)d_in[1];
  const float* lb = (const float*)d_in[2];
  float* out = (float*)d_out;

  const int total = in_sizes[0];
  const size_t need = (size_t)(TG_FLOATS + ST_FLOATS) * 4;

  if (total == B_ * N_ && ws_size >= need) {
    float* Tg = (float*)d_ws;
    float* st = Tg + TG_FLOATS;
    diffks_phase1<<<B_ * S_, 1024, 0, stream>>>(f0, lb, x, Tg);
    diffks_phase2<<<B_, 832, 0, stream>>>(Tg, st);
    diffks_phase3<<<B_ * S_, 256, 0, stream>>>(f0, lb, x, st, out);
  } else {
    const int N = total / B_;
    float* cw = (float*)d_ws;
    diffks_coeff_fb<<<(total + 255) / 256, 256, 0, stream>>>(f0, lb, cw, total, N - 1);
    diffks_scan_fb<<<B_, 64, 0, stream>>>(x, cw, out, N);
  }
}